// Round 8
// baseline (226.613 us; speedup 1.0000x reference)
//
#include <hip/hip_runtime.h>
#include <hip/hip_cooperative_groups.h>

namespace cg = cooperative_groups;

#define Bn 8
#define Sn 8192
#define Dn 128
#define NCn 128

typedef _Float16 f16;
typedef f16 f16x2 __attribute__((ext_vector_type(2)));
typedef f16 f16x4 __attribute__((ext_vector_type(4)));
typedef float f32x4 __attribute__((ext_vector_type(4)));

static __device__ __forceinline__ f32x4 mfma16(f16x4 a, f16x4 b, f32x4 c) {
  return __builtin_amdgcn_mfma_f32_16x16x16f16(a, b, c, 0, 0, 0);
}

union UU { uint4 u; f16x2 h[4]; };

// Validated fragment conventions for mfma_f32_16x16x16f16 (rounds 0,2,3,4,6,7):
//   af from P rows: af[j] = P[rt*16 + (l&15)][kk*16 + 4*(l>>4)+j]
//   bf from Q rows: bf[j] = Q[ct*16 + (l&15)][kk*16 + 4*(l>>4)+j]
//   result R = P.Q^T lands as R[rt*16 + 4*(l>>4)+j][ct*16 + (l&15)]  (D-frag)
//   D-frag of u == A-frag of u^T (in-register); packed D-frag [(r*8+c)*64+lane]
//   == B-frag for row-contraction.

// ============================================================================
// FUSED single-kernel pipeline (cooperative). 512 blocks x 512 threads,
// 2 blocks/CU co-resident. Phases: prep | Z | scan | out, grid.sync between.
// ============================================================================
__global__ __launch_bounds__(512, 4) void k_fused(
    const float* __restrict__ x, const float* __restrict__ gw, const float* __restrict__ gb,
    const float* __restrict__ Wq, const float* __restrict__ Wk,
    const float* __restrict__ Wv, const float* __restrict__ Wout,
    f16* __restrict__ Amat, f16* __restrict__ r2, float* __restrict__ gavg,
    f16x4* __restrict__ wtg, uint* __restrict__ pbuf, float* __restrict__ outp) {
  cg::grid_group grid = cg::this_grid();
  __shared__ __align__(16) char raw[34048];
  f16(*Xs)[136] = (f16(*)[136])raw;          // 17408 B
  f16x4* vP = (f16x4*)(raw + 17408);         // 16384 B (zP in out-phase)
  float* gs = (float*)(raw + 33792);         // 256 B

  const int blk = blockIdx.x, tid = threadIdx.x;
  const int w = tid >> 6, lane = tid & 63, r16 = lane & 15, g4 = lane >> 4;
  const int grp = blk & 127, mbase = blk >> 7;  // grp: (b,seg); mbase in {0..3}
  const int b = grp >> 4, seg = grp & 15;

  // ---------------- phase P: prep (blocks 0-63, waves 0-1) ----------------
  if (blk < 64 && w < 2) {
    const int ti = blk >> 3, tj = blk & 7;
    f32x4 acc = {};
    if (w == 0) {  // Amat = Wq^T Wk
#pragma unroll
      for (int kk = 0; kk < 8; ++kk) {
        f16x4 af, bf;
#pragma unroll
        for (int j = 0; j < 4; ++j) {
          af[j] = (f16)Wq[(kk * 16 + g4 * 4 + j) * 128 + ti * 16 + r16];
          bf[j] = (f16)Wk[(kk * 16 + g4 * 4 + j) * 128 + tj * 16 + r16];
        }
        acc = mfma16(af, bf, acc);
      }
#pragma unroll
      for (int j = 0; j < 4; ++j)
        Amat[(ti * 16 + g4 * 4 + j) * 128 + tj * 16 + r16] = (f16)acc[j];
    } else {  // r2 = Wout Wv
#pragma unroll
      for (int kk = 0; kk < 8; ++kk) {
        f16x4 af, bf;
        float4 a4 = *(const float4*)(Wout + (ti * 16 + r16) * 128 + kk * 16 + g4 * 4);
        af[0] = (f16)a4.x; af[1] = (f16)a4.y; af[2] = (f16)a4.z; af[3] = (f16)a4.w;
#pragma unroll
        for (int j = 0; j < 4; ++j)
          bf[j] = (f16)Wv[(kk * 16 + g4 * 4 + j) * 128 + tj * 16 + r16];
        acc = mfma16(af, bf, acc);
      }
#pragma unroll
      for (int j = 0; j < 4; ++j)
        r2[(ti * 16 + g4 * 4 + j) * 128 + tj * 16 + r16] = (f16)acc[j];
    }
  }
  grid.sync();

  // ---------------- phase Z: gate + u,v + Z for 2 chunks ----------------
#pragma unroll
  for (int mm = 0; mm < 2; ++mm) {
    const int c = seg * 8 + mbase + mm * 4;
    {
      int s = tid >> 3, sub = tid & 7;
      const float* xrow = x + ((size_t)b * Sn + (size_t)c * 64 + s) * Dn;
      float gpart = 0.f;
#pragma unroll
      for (int i = 0; i < 4; ++i) {
        int col = sub * 4 + i * 32;
        float4 v = *(const float4*)(xrow + col);
        float4 g = *(const float4*)(gw + col);
        gpart += v.x * g.x + v.y * g.y + v.z * g.z + v.w * g.w;
        f16x4 hh = {(f16)v.x, (f16)v.y, (f16)v.z, (f16)v.w};
        *(f16x4*)&Xs[s][col] = hh;
      }
      gpart += __shfl_xor(gpart, 1);
      gpart += __shfl_xor(gpart, 2);
      gpart += __shfl_xor(gpart, 4);
      if (sub == 0) gs[s] = 1.f / (1.f + __expf(-(gpart + gb[0])));
    }
    __syncthreads();
    if (tid == 0) {
      float sum = 0.f;
#pragma unroll
      for (int i = 0; i < 64; ++i) sum += gs[i];
      gavg[b * NCn + c] = sum * (1.f / 64.f);
    }
    f32x4 uacc[4] = {}, vacc[4] = {};
#pragma unroll
    for (int kk = 0; kk < 8; ++kk) {
      f16x4 bu = *(const f16x4*)&Amat[(w * 16 + r16) * 128 + kk * 16 + g4 * 4];
      f16x4 bv = *(const f16x4*)&r2[(w * 16 + r16) * 128 + kk * 16 + g4 * 4];
#pragma unroll
      for (int mr = 0; mr < 4; ++mr) {
        f16x4 af = *(f16x4*)&Xs[mr * 16 + r16][kk * 16 + g4 * 4];
        uacc[mr] = mfma16(af, bu, uacc[mr]);
        vacc[mr] = mfma16(af, bv, vacc[mr]);
      }
    }
    f16x4 ua[4];
#pragma unroll
    for (int mr = 0; mr < 4; ++mr) {
      float g0 = gs[mr * 16 + g4 * 4 + 0], g1 = gs[mr * 16 + g4 * 4 + 1];
      float g2 = gs[mr * 16 + g4 * 4 + 2], g3 = gs[mr * 16 + g4 * 4 + 3];
      f16x4 uh = {(f16)(uacc[mr][0] * g0), (f16)(uacc[mr][1] * g1),
                  (f16)(uacc[mr][2] * g2), (f16)(uacc[mr][3] * g3)};
      ua[mr] = uh;
      f16x4 vh = {(f16)vacc[mr][0], (f16)vacc[mr][1], (f16)vacc[mr][2], (f16)vacc[mr][3]};
      vP[(mr * 8 + w) * 64 + lane] = vh;
    }
    __syncthreads();
    f32x4 z[8] = {};
#pragma unroll
    for (int ks = 0; ks < 4; ++ks)
#pragma unroll
      for (int ct = 0; ct < 8; ++ct)
        z[ct] = mfma16(ua[ks], vP[(ks * 8 + ct) * 64 + lane], z[ct]);
    f16x4* wdst = wtg + (size_t)(b * NCn + c) * 4096;
#pragma unroll
    for (int ct = 0; ct < 8; ++ct) {
      f16x4 zh = {(f16)z[ct][0], (f16)z[ct][1], (f16)z[ct][2], (f16)z[ct][3]};
      wdst[(w * 8 + ct) * 64 + lane] = zh;
    }
    __syncthreads();
  }
  grid.sync();

  // ---------------- phase S: scan (blocks 0-127), 16-deep prefetch ----------------
  if (blk < 128) {
    const int sid = blk * 512 + tid;  // 0..65535
    const int sb = sid >> 13, e = sid & 8191;
    const uint* wp = (const uint*)wtg + (size_t)sb * (NCn * 8192) + e;
    uint* pp = pbuf + (size_t)sb * (15 * 8192) + e;
    const float* ga = gavg + sb * NCn;
    float M0 = 0.f, M1 = 0.f;
    uint ubuf[16];
    float abuf[16];
#pragma unroll
    for (int i = 0; i < 16; ++i) {
      ubuf[i] = wp[(size_t)i * 8192];
      abuf[i] = ga[i];
    }
    for (int g = 0; g < 8; ++g) {
      uint un[16];
      float an[16];
      if (g < 7) {
#pragma unroll
        for (int i = 0; i < 16; ++i) {
          un[i] = wp[(size_t)((g + 1) * 16 + i) * 8192];
          an[i] = ga[(g + 1) * 16 + i];
        }
      }
#pragma unroll
      for (int i = 0; i < 16; ++i) {
        int cc = g * 16 + i;
        f16x2 wv = __builtin_bit_cast(f16x2, ubuf[i]);
        float dd = 1.f - abuf[i];
        M0 = dd * M0 + (float)wv[0];
        M1 = dd * M1 + (float)wv[1];
        if ((cc & 7) == 7 && cc < 120) {
          f16x2 mv = {(f16)M0, (f16)M1};
          pp[(size_t)(cc >> 3) * 8192] = __builtin_bit_cast(uint, mv);
        }
      }
      if (g < 7) {
#pragma unroll
        for (int i = 0; i < 16; ++i) { ubuf[i] = un[i]; abuf[i] = an[i]; }
      }
    }
  }
  grid.sync();

  // ---------------- phase O: out for 2 chunks ----------------
  const uint4* wtg4 = (const uint4*)wtg;
  const uint4* pbuf4 = (const uint4*)pbuf;
  f16x4* zP = vP;
#pragma unroll
  for (int mm = 0; mm < 2; ++mm) {
    const int m = mbase + mm * 4;
    const int c = seg * 8 + m;
    if (mm) __syncthreads();  // prior iter's MFMA reads of Xs/zP done
    {
      int s = tid >> 3, sub = tid & 7;
      const float* xrow = x + ((size_t)b * Sn + (size_t)c * 64 + s) * Dn;
#pragma unroll
      for (int i = 0; i < 4; ++i) {
        int col = sub * 4 + i * 32;
        float4 v = *(const float4*)(xrow + col);
        f16x4 hh = {(f16)v.x, (f16)v.y, (f16)v.z, (f16)v.w};
        *(f16x4*)&Xs[s][col] = hh;
      }
    }
    float d[8], sfac[8];
#pragma unroll
    for (int t = 0; t < 8; ++t)
      d[t] = (t < m) ? (1.f - gavg[b * NCn + seg * 8 + t]) : 1.f;
    sfac[7] = 1.f;
#pragma unroll
    for (int t = 6; t >= 0; --t) sfac[t] = sfac[t + 1] * d[t + 1];
    const float sP = sfac[0] * d[0];
    const uint4* Zbase = wtg4 + (size_t)(b * NCn + seg * 8) * 2048;
    const uint4* Pp = pbuf4 + (size_t)(b * 15 + (seg > 0 ? seg - 1 : 0)) * 2048;
    const int mr = w & 3, cb = (w >> 2) * 4;
    f32x4 acc[4] = {};
#pragma unroll
    for (int half = 0; half < 2; ++half) {
      if (half) __syncthreads();
#pragma unroll
      for (int i = 0; i < 2; ++i) {
        int idx = tid + i * 512;
        int src = half * 1024 + idx;
        float a8[8] = {0.f, 0.f, 0.f, 0.f, 0.f, 0.f, 0.f, 0.f};
        if (seg > 0) {
          UU z; z.u = Pp[src];
#pragma unroll
          for (int q = 0; q < 4; ++q) {
            a8[2 * q] += sP * (float)z.h[q][0];
            a8[2 * q + 1] += sP * (float)z.h[q][1];
          }
        }
#pragma unroll
        for (int t = 0; t < 8; ++t)
          if (t < m) {
            UU z; z.u = Zbase[(size_t)t * 2048 + src];
#pragma unroll
            for (int q = 0; q < 4; ++q) {
              a8[2 * q] += sfac[t] * (float)z.h[q][0];
              a8[2 * q + 1] += sfac[t] * (float)z.h[q][1];
            }
          }
        UU o;
#pragma unroll
        for (int q = 0; q < 4; ++q)
          o.h[q] = (f16x2){(f16)a8[2 * q], (f16)a8[2 * q + 1]};
        ((uint4*)zP)[idx] = o.u;
      }
      __syncthreads();
#pragma unroll
      for (int kk = 0; kk < 4; ++kk) {
        f16x4 af = *(f16x4*)&Xs[mr * 16 + r16][(half * 4 + kk) * 16 + g4 * 4];
#pragma unroll
        for (int t = 0; t < 4; ++t)
          acc[t] = mfma16(af, zP[(kk * 8 + cb + t) * 64 + lane], acc[t]);
      }
    }
    float* obase = outp + ((size_t)b * Sn + (size_t)c * 64 + mr * 16 + g4 * 4) * Dn;
#pragma unroll
    for (int t = 0; t < 4; ++t)
#pragma unroll
      for (int j = 0; j < 4; ++j)
        obase[(size_t)j * Dn + (cb + t) * 16 + r16] = acc[t][j];
  }
}

// ============================================================================
// Fallback 4-kernel path (round-7, validated)
// ============================================================================
__global__ __launch_bounds__(64) void k_prep(
    const float* __restrict__ Wq, const float* __restrict__ Wk,
    const float* __restrict__ Wv, const float* __restrict__ Wout,
    f16* __restrict__ Amat, f16* __restrict__ r2) {
  const int blk = blockIdx.x;
  const int which = blk >> 6;
  const int t = blk & 63, ti = t >> 3, tj = t & 7;
  const int lane = threadIdx.x & 63, r16 = lane & 15, g4 = lane >> 4;
  f32x4 acc = {};
  if (which == 0) {
#pragma unroll
    for (int kk = 0; kk < 8; ++kk) {
      f16x4 af, bf;
#pragma unroll
      for (int j = 0; j < 4; ++j) {
        af[j] = (f16)Wq[(kk * 16 + g4 * 4 + j) * 128 + ti * 16 + r16];
        bf[j] = (f16)Wk[(kk * 16 + g4 * 4 + j) * 128 + tj * 16 + r16];
      }
      acc = mfma16(af, bf, acc);
    }
  } else {
#pragma unroll
    for (int kk = 0; kk < 8; ++kk) {
      f16x4 af, bf;
      float4 a4 = *(const float4*)(Wout + (ti * 16 + r16) * 128 + kk * 16 + g4 * 4);
      af[0] = (f16)a4.x; af[1] = (f16)a4.y; af[2] = (f16)a4.z; af[3] = (f16)a4.w;
#pragma unroll
      for (int j = 0; j < 4; ++j)
        bf[j] = (f16)Wv[(kk * 16 + g4 * 4 + j) * 128 + tj * 16 + r16];
      acc = mfma16(af, bf, acc);
    }
  }
  f16* dst = which ? r2 : Amat;
#pragma unroll
  for (int j = 0; j < 4; ++j)
    dst[(ti * 16 + g4 * 4 + j) * 128 + tj * 16 + r16] = (f16)acc[j];
}

__global__ __launch_bounds__(512, 8) void k_phase1(
    const float* __restrict__ x, const float* __restrict__ gw, const float* __restrict__ gb,
    const f16* __restrict__ Amat, const f16* __restrict__ r2,
    f16x4* __restrict__ wtg, float* __restrict__ gavg) {
  __shared__ __align__(16) f16 Xs[64][136];
  __shared__ __align__(16) f16x4 vP[2048];
  __shared__ float gs[64];
  const int h = blockIdx.x;
  const int grp = h & 127, m = h >> 7;
  const int b = grp >> 4, seg = grp & 15;
  const int c = seg * 8 + m;
  const int tid = threadIdx.x;
  {
    int s = tid >> 3, sub = tid & 7;
    const float* xrow = x + ((size_t)b * Sn + (size_t)c * 64 + s) * Dn;
    float gpart = 0.f;
#pragma unroll
    for (int i = 0; i < 4; ++i) {
      int col = sub * 4 + i * 32;
      float4 v = *(const float4*)(xrow + col);
      float4 g = *(const float4*)(gw + col);
      gpart += v.x * g.x + v.y * g.y + v.z * g.z + v.w * g.w;
      f16x4 hh = {(f16)v.x, (f16)v.y, (f16)v.z, (f16)v.w};
      *(f16x4*)&Xs[s][col] = hh;
    }
    gpart += __shfl_xor(gpart, 1);
    gpart += __shfl_xor(gpart, 2);
    gpart += __shfl_xor(gpart, 4);
    if (sub == 0) gs[s] = 1.f / (1.f + __expf(-(gpart + gb[0])));
  }
  __syncthreads();
  if (tid == 0) {
    float sum = 0.f;
#pragma unroll
    for (int i = 0; i < 64; ++i) sum += gs[i];
    gavg[b * NCn + c] = sum * (1.f / 64.f);
  }
  const int w = tid >> 6, lane = tid & 63, r16 = lane & 15, g4 = lane >> 4;
  f32x4 uacc[4] = {}, vacc[4] = {};
#pragma unroll
  for (int kk = 0; kk < 8; ++kk) {
    f16x4 bu = *(const f16x4*)&Amat[(w * 16 + r16) * 128 + kk * 16 + g4 * 4];
    f16x4 bv = *(const f16x4*)&r2[(w * 16 + r16) * 128 + kk * 16 + g4 * 4];
#pragma unroll
    for (int mr = 0; mr < 4; ++mr) {
      f16x4 af = *(f16x4*)&Xs[mr * 16 + r16][kk * 16 + g4 * 4];
      uacc[mr] = mfma16(af, bu, uacc[mr]);
      vacc[mr] = mfma16(af, bv, vacc[mr]);
    }
  }
  f16x4 ua[4];
#pragma unroll
  for (int mr = 0; mr < 4; ++mr) {
    float g0 = gs[mr * 16 + g4 * 4 + 0], g1 = gs[mr * 16 + g4 * 4 + 1];
    float g2 = gs[mr * 16 + g4 * 4 + 2], g3 = gs[mr * 16 + g4 * 4 + 3];
    f16x4 uh = {(f16)(uacc[mr][0] * g0), (f16)(uacc[mr][1] * g1),
                (f16)(uacc[mr][2] * g2), (f16)(uacc[mr][3] * g3)};
    ua[mr] = uh;
    f16x4 vh = {(f16)vacc[mr][0], (f16)vacc[mr][1], (f16)vacc[mr][2], (f16)vacc[mr][3]};
    vP[(mr * 8 + w) * 64 + lane] = vh;
  }
  __syncthreads();
  f32x4 z[8] = {};
#pragma unroll
  for (int ks = 0; ks < 4; ++ks)
#pragma unroll
    for (int ct = 0; ct < 8; ++ct)
      z[ct] = mfma16(ua[ks], vP[(ks * 8 + ct) * 64 + lane], z[ct]);
  f16x4* wdst = wtg + (size_t)(b * NCn + c) * 4096;
#pragma unroll
  for (int ct = 0; ct < 8; ++ct) {
    f16x4 zh = {(f16)z[ct][0], (f16)z[ct][1], (f16)z[ct][2], (f16)z[ct][3]};
    wdst[(w * 8 + ct) * 64 + lane] = zh;
  }
}

__global__ __launch_bounds__(256) void k_scan(
    const uint* __restrict__ wtg, const float* __restrict__ gavg, uint* __restrict__ pbuf) {
  const int blk = blockIdx.x;
  const int b = blk >> 5;
  const int e = (blk & 31) * 256 + threadIdx.x;
  const uint* wp = wtg + (size_t)b * (NCn * 8192) + e;
  uint* pp = pbuf + (size_t)b * (15 * 8192) + e;
  const float* ga = gavg + b * NCn;
  float M0 = 0.f, M1 = 0.f;
  uint ubuf[32];
  float abuf[32];
#pragma unroll
  for (int i = 0; i < 32; ++i) {
    ubuf[i] = wp[(size_t)i * 8192];
    abuf[i] = ga[i];
  }
  for (int g = 0; g < 4; ++g) {
    uint un[32];
    float an[32];
    if (g < 3) {
#pragma unroll
      for (int i = 0; i < 32; ++i) {
        un[i] = wp[(size_t)((g + 1) * 32 + i) * 8192];
        an[i] = ga[(g + 1) * 32 + i];
      }
    }
#pragma unroll
    for (int i = 0; i < 32; ++i) {
      int cc = g * 32 + i;
      f16x2 wv = __builtin_bit_cast(f16x2, ubuf[i]);
      float dd = 1.f - abuf[i];
      M0 = dd * M0 + (float)wv[0];
      M1 = dd * M1 + (float)wv[1];
      if ((cc & 7) == 7 && cc < 120) {
        f16x2 mv = {(f16)M0, (f16)M1};
        pp[(size_t)(cc >> 3) * 8192] = __builtin_bit_cast(uint, mv);
      }
    }
    if (g < 3) {
#pragma unroll
      for (int i = 0; i < 32; ++i) { ubuf[i] = un[i]; abuf[i] = an[i]; }
    }
  }
}

__global__ __launch_bounds__(512, 8) void k_out(
    const float* __restrict__ x, const uint4* __restrict__ wtg4,
    const uint4* __restrict__ pbuf4, const float* __restrict__ gavg,
    float* __restrict__ outp) {
  __shared__ __align__(16) f16 Xs[64][136];
  __shared__ __align__(16) f16x4 zP[2048];
  const int h = blockIdx.x;
  const int grp = h & 127, m = h >> 7;
  const int b = grp >> 4, seg = grp & 15;
  const int c = seg * 8 + m;
  const int tid = threadIdx.x;
  {
    int s = tid >> 3, sub = tid & 7;
    const float* xrow = x + ((size_t)b * Sn + (size_t)c * 64 + s) * Dn;
#pragma unroll
    for (int i = 0; i < 4; ++i) {
      int col = sub * 4 + i * 32;
      float4 v = *(const float4*)(xrow + col);
      f16x4 hh = {(f16)v.x, (f16)v.y, (f16)v.z, (f16)v.w};
      *(f16x4*)&Xs[s][col] = hh;
    }
  }
  float d[8], sfac[8];
#pragma unroll
  for (int t = 0; t < 8; ++t)
    d[t] = (t < m) ? (1.f - gavg[b * NCn + seg * 8 + t]) : 1.f;
  sfac[7] = 1.f;
#pragma unroll
  for (int t = 6; t >= 0; --t) sfac[t] = sfac[t + 1] * d[t + 1];
  const float sP = sfac[0] * d[0];
  const uint4* Zbase = wtg4 + (size_t)(b * NCn + seg * 8) * 2048;
  const uint4* Pp = pbuf4 + (size_t)(b * 15 + (seg > 0 ? seg - 1 : 0)) * 2048;
  const int w = tid >> 6, lane = tid & 63, r16 = lane & 15, g4 = lane >> 4;
  const int mr = w & 3, cb = (w >> 2) * 4;
  f32x4 acc[4] = {};
#pragma unroll
  for (int half = 0; half < 2; ++half) {
    if (half) __syncthreads();
#pragma unroll
    for (int i = 0; i < 2; ++i) {
      int idx = tid + i * 512;
      int src = half * 1024 + idx;
      float a8[8] = {0.f, 0.f, 0.f, 0.f, 0.f, 0.f, 0.f, 0.f};
      if (seg > 0) {
        UU z; z.u = Pp[src];
#pragma unroll
        for (int q = 0; q < 4; ++q) {
          a8[2 * q] += sP * (float)z.h[q][0];
          a8[2 * q + 1] += sP * (float)z.h[q][1];
        }
      }
#pragma unroll
      for (int t = 0; t < 8; ++t)
        if (t < m) {
          UU z; z.u = Zbase[(size_t)t * 2048 + src];
#pragma unroll
          for (int q = 0; q < 4; ++q) {
            a8[2 * q] += sfac[t] * (float)z.h[q][0];
            a8[2 * q + 1] += sfac[t] * (float)z.h[q][1];
          }
        }
      UU o;
#pragma unroll
      for (int q = 0; q < 4; ++q)
        o.h[q] = (f16x2){(f16)a8[2 * q], (f16)a8[2 * q + 1]};
      ((uint4*)zP)[idx] = o.u;
    }
    __syncthreads();
#pragma unroll
    for (int kk = 0; kk < 4; ++kk) {
      f16x4 af = *(f16x4*)&Xs[mr * 16 + r16][(half * 4 + kk) * 16 + g4 * 4];
#pragma unroll
      for (int t = 0; t < 4; ++t)
        acc[t] = mfma16(af, zP[(kk * 8 + cb + t) * 64 + lane], acc[t]);
    }
  }
  float* obase = outp + ((size_t)b * Sn + (size_t)c * 64 + mr * 16 + g4 * 4) * Dn;
#pragma unroll
  for (int t = 0; t < 4; ++t)
#pragma unroll
    for (int j = 0; j < 4; ++j)
      obase[(size_t)j * Dn + (cb + t) * 16 + r16] = acc[t][j];
}

extern "C" void kernel_launch(void* const* d_in, const int* in_sizes, int n_in,
                              void* d_out, int out_size, void* d_ws, size_t ws_size,
                              hipStream_t stream) {
  const float* x = (const float*)d_in[0];
  const float* Wq = (const float*)d_in[1];
  const float* Wk = (const float*)d_in[2];
  const float* Wv = (const float*)d_in[3];
  const float* gw = (const float*)d_in[4];
  const float* gb = (const float*)d_in[5];
  const float* Wout = (const float*)d_in[6];

  char* ws = (char*)d_ws;
  f16* Amat = (f16*)(ws + 0);                  // 32 KB
  f16* r2 = (f16*)(ws + 32768);                // 32 KB
  float* gavg = (float*)(ws + 65536);          // 4 KB
  f16* wtg = (f16*)(ws + 69632);               // 33.5 MB (Z, packed frags)
  f16* pbuf = (f16*)(ws + 69632 + 33554432);   // 3.84 MB (segment carries)
  float* outp = (float*)d_out;

  f16x4* wtg4 = (f16x4*)wtg;
  uint* pbufu = (uint*)pbuf;
  void* args[] = {(void*)&x, (void*)&gw, (void*)&gb, (void*)&Wq, (void*)&Wk,
                  (void*)&Wv, (void*)&Wout, (void*)&Amat, (void*)&r2,
                  (void*)&gavg, (void*)&wtg4, (void*)&pbufu, (void*)&outp};
  hipError_t err = hipLaunchCooperativeKernel((const void*)k_fused, dim3(512), dim3(512),
                                              args, 0, stream);
  if (err != hipSuccess) {
    // fallback: validated 4-kernel pipeline
    k_prep<<<dim3(128), dim3(64), 0, stream>>>(Wq, Wk, Wv, Wout, Amat, r2);
    k_phase1<<<dim3(Bn * NCn), dim3(512), 0, stream>>>(x, gw, gb, Amat, r2, (f16x4*)wtg, gavg);
    k_scan<<<dim3(256), dim3(256), 0, stream>>>((const uint*)wtg, gavg, (uint*)pbuf);
    k_out<<<dim3(Bn * NCn), dim3(512), 0, stream>>>(x, (const uint4*)wtg, (const uint4*)pbuf,
                                                    gavg, (float*)d_out);
  }
}

// Round 9
// 64.923 us; speedup vs baseline: 3.4905x; 3.4905x over previous
//
#include <hip/hip_runtime.h>

#define Bn 8
#define Sn 8192
#define Dn 128
#define NCn 128

typedef _Float16 f16;
typedef f16 f16x2 __attribute__((ext_vector_type(2)));
typedef f16 f16x4 __attribute__((ext_vector_type(4)));
typedef float f32x4 __attribute__((ext_vector_type(4)));

static __device__ __forceinline__ f32x4 mfma16(f16x4 a, f16x4 b, f32x4 c) {
  return __builtin_amdgcn_mfma_f32_16x16x16f16(a, b, c, 0, 0, 0);
}

union UU { uint4 u; f16x2 h[4]; f16x4 q[2]; };

// Validated fragment conventions for mfma_f32_16x16x16f16 (rounds 0,2,3,4,6,7):
//   A-frag: lane l, reg j = A_op[l&15][4*(l>>4)+j]
//   B-frag: lane l, reg j = B_op[4*(l>>4)+j][l&15]
//   D-frag: lane l, reg j = D[4*(l>>4)+j][l&15]
//   D-frag of u == A-frag of u^T (in-register); packed D-frag [(r*8+c)*64+lane]
//   == B-frag for row-contraction (validated rounds 3-7).

// ---- precompute: 128 blocks x 1 wave (validated r7) ----
__global__ __launch_bounds__(64) void k_prep(
    const float* __restrict__ Wq, const float* __restrict__ Wk,
    const float* __restrict__ Wv, const float* __restrict__ Wout,
    f16* __restrict__ Amat, f16* __restrict__ r2) {
  const int blk = blockIdx.x;
  const int which = blk >> 6;
  const int t = blk & 63, ti = t >> 3, tj = t & 7;
  const int lane = threadIdx.x & 63, r16 = lane & 15, g4 = lane >> 4;
  f32x4 acc = {};
  if (which == 0) {
#pragma unroll
    for (int kk = 0; kk < 8; ++kk) {
      f16x4 af, bf;
#pragma unroll
      for (int j = 0; j < 4; ++j) {
        af[j] = (f16)Wq[(kk * 16 + g4 * 4 + j) * 128 + ti * 16 + r16];
        bf[j] = (f16)Wk[(kk * 16 + g4 * 4 + j) * 128 + tj * 16 + r16];
      }
      acc = mfma16(af, bf, acc);
    }
  } else {
#pragma unroll
    for (int kk = 0; kk < 8; ++kk) {
      f16x4 af, bf;
      float4 a4 = *(const float4*)(Wout + (ti * 16 + r16) * 128 + kk * 16 + g4 * 4);
      af[0] = (f16)a4.x; af[1] = (f16)a4.y; af[2] = (f16)a4.z; af[3] = (f16)a4.w;
#pragma unroll
      for (int j = 0; j < 4; ++j)
        bf[j] = (f16)Wv[(kk * 16 + g4 * 4 + j) * 128 + tj * 16 + r16];
      acc = mfma16(af, bf, acc);
    }
  }
  f16* dst = which ? r2 : Amat;
#pragma unroll
  for (int j = 0; j < 4; ++j)
    dst[(ti * 16 + g4 * 4 + j) * 128 + tj * 16 + r16] = (f16)acc[j];
}

// ---- fused: gate, u = x Amat^T, v = x r2^T, Z = (g.u)^T v (validated r7)
// + NEW: writes xh (f16 copy of the chunk) for k_outseg. ----
__global__ __launch_bounds__(512, 8) void k_phase1(
    const float* __restrict__ x, const float* __restrict__ gw, const float* __restrict__ gb,
    const f16* __restrict__ Amat, const f16* __restrict__ r2,
    f16x4* __restrict__ wtg, float* __restrict__ gavg, f16* __restrict__ xh) {
  __shared__ __align__(16) f16 Xs[64][136];
  __shared__ __align__(16) f16x4 vP[2048];
  __shared__ float gs[64];
  const int h = blockIdx.x;
  const int grp = h & 127, m = h >> 7;
  const int b = grp >> 4, seg = grp & 15;
  const int c = seg * 8 + m;
  const int tid = threadIdx.x;
  {
    int s = tid >> 3, sub = tid & 7;
    const float* xrow = x + ((size_t)b * Sn + (size_t)c * 64 + s) * Dn;
    f16* xhrow = xh + (size_t)(b * NCn + c) * 8192 + s * 128;
    float gpart = 0.f;
#pragma unroll
    for (int i = 0; i < 4; ++i) {
      int col = sub * 4 + i * 32;
      float4 v = *(const float4*)(xrow + col);
      float4 g = *(const float4*)(gw + col);
      gpart += v.x * g.x + v.y * g.y + v.z * g.z + v.w * g.w;
      f16x4 hh = {(f16)v.x, (f16)v.y, (f16)v.z, (f16)v.w};
      *(f16x4*)&Xs[s][col] = hh;
      *(f16x4*)&xhrow[col] = hh;
    }
    gpart += __shfl_xor(gpart, 1);
    gpart += __shfl_xor(gpart, 2);
    gpart += __shfl_xor(gpart, 4);
    if (sub == 0) gs[s] = 1.f / (1.f + __expf(-(gpart + gb[0])));
  }
  __syncthreads();
  if (tid == 0) {
    float sum = 0.f;
#pragma unroll
    for (int i = 0; i < 64; ++i) sum += gs[i];
    gavg[b * NCn + c] = sum * (1.f / 64.f);
  }
  const int w = tid >> 6, lane = tid & 63, r16 = lane & 15, g4 = lane >> 4;
  f32x4 uacc[4] = {}, vacc[4] = {};
#pragma unroll
  for (int kk = 0; kk < 8; ++kk) {
    f16x4 bu = *(const f16x4*)&Amat[(w * 16 + r16) * 128 + kk * 16 + g4 * 4];
    f16x4 bv = *(const f16x4*)&r2[(w * 16 + r16) * 128 + kk * 16 + g4 * 4];
#pragma unroll
    for (int mr = 0; mr < 4; ++mr) {
      f16x4 af = *(f16x4*)&Xs[mr * 16 + r16][kk * 16 + g4 * 4];
      uacc[mr] = mfma16(af, bu, uacc[mr]);
      vacc[mr] = mfma16(af, bv, vacc[mr]);
    }
  }
  f16x4 ua[4];
#pragma unroll
  for (int mr = 0; mr < 4; ++mr) {
    float g0 = gs[mr * 16 + g4 * 4 + 0], g1 = gs[mr * 16 + g4 * 4 + 1];
    float g2 = gs[mr * 16 + g4 * 4 + 2], g3 = gs[mr * 16 + g4 * 4 + 3];
    f16x4 uh = {(f16)(uacc[mr][0] * g0), (f16)(uacc[mr][1] * g1),
                (f16)(uacc[mr][2] * g2), (f16)(uacc[mr][3] * g3)};
    ua[mr] = uh;
    f16x4 vh = {(f16)vacc[mr][0], (f16)vacc[mr][1], (f16)vacc[mr][2], (f16)vacc[mr][3]};
    vP[(mr * 8 + w) * 64 + lane] = vh;
  }
  __syncthreads();
  f32x4 z[8] = {};
#pragma unroll
  for (int ks = 0; ks < 4; ++ks)
#pragma unroll
    for (int ct = 0; ct < 8; ++ct)
      z[ct] = mfma16(ua[ks], vP[(ks * 8 + ct) * 64 + lane], z[ct]);
  f16x4* wdst = wtg + (size_t)(b * NCn + c) * 4096;
#pragma unroll
  for (int ct = 0; ct < 8; ++ct) {
    f16x4 zh = {(f16)z[ct][0], (f16)z[ct][1], (f16)z[ct][2], (f16)z[ct][3]};
    wdst[(w * 8 + ct) * 64 + lane] = zh;
  }
}

// ---- scan: segment-boundary carries P_s (validated r7, 32-deep prefetch) ----
__global__ __launch_bounds__(256) void k_scan(
    const uint* __restrict__ wtg, const float* __restrict__ gavg, uint* __restrict__ pbuf) {
  const int blk = blockIdx.x;
  const int b = blk >> 5;
  const int e = (blk & 31) * 256 + threadIdx.x;
  const uint* wp = wtg + (size_t)b * (NCn * 8192) + e;
  uint* pp = pbuf + (size_t)b * (15 * 8192) + e;
  const float* ga = gavg + b * NCn;
  float M0 = 0.f, M1 = 0.f;
  uint ubuf[32];
  float abuf[32];
#pragma unroll
  for (int i = 0; i < 32; ++i) {
    ubuf[i] = wp[(size_t)i * 8192];
    abuf[i] = ga[i];
  }
  for (int g = 0; g < 4; ++g) {
    uint un[32];
    float an[32];
    if (g < 3) {
#pragma unroll
      for (int i = 0; i < 32; ++i) {
        un[i] = wp[(size_t)((g + 1) * 32 + i) * 8192];
        an[i] = ga[(g + 1) * 32 + i];
      }
    }
#pragma unroll
    for (int i = 0; i < 32; ++i) {
      int cc = g * 32 + i;
      f16x2 wv = __builtin_bit_cast(f16x2, ubuf[i]);
      float dd = 1.f - abuf[i];
      M0 = dd * M0 + (float)wv[0];
      M1 = dd * M1 + (float)wv[1];
      if ((cc & 7) == 7 && cc < 120) {
        f16x2 mv = {(f16)M0, (f16)M1};
        pp[(size_t)(cc >> 3) * 8192] = __builtin_bit_cast(uint, mv);
      }
    }
    if (g < 3) {
#pragma unroll
      for (int i = 0; i < 32; ++i) { ubuf[i] = un[i]; abuf[i] = an[i]; }
    }
  }
}

// ---- NEW: segment-owner out. Block (b,seg,quarter): M (128x32, packed frags)
// lives in f32 LDS; per chunk: GEMM out_c = x_c M then M = d*M + Z_c.
// Z read exactly once grid-wide. ----
__global__ __launch_bounds__(512, 4) void k_outseg(
    const f16* __restrict__ xh, const uint4* __restrict__ wtg4,
    const uint4* __restrict__ pbuf4, const float* __restrict__ gavg,
    float* __restrict__ outp) {
  __shared__ __align__(16) f16 Xs[64][136];   // 17408 B
  __shared__ __align__(16) float Mf[4096];    // 16384 B (f32 accumulator, packed)
  __shared__ __align__(16) f16x4 Mh4[1024];   // 8192 B  (f16 copy for GEMM)
  const int blk = blockIdx.x;
  const int q = blk & 3, seg = (blk >> 2) & 15, b = blk >> 6;
  const int tid = threadIdx.x;
  const int w = tid >> 6, lane = tid & 63, r16 = lane & 15, g4 = lane >> 4;
  const int mr = w & 3, tq = w >> 2;  // wave's out tile: rows mr*16.., col tile q*2+tq

  // this thread's uint4 slot in the quarter (16 tiles x 32 uint4)
  const int lt = tid >> 5;                           // local tile 0..15
  const int gtile = (lt >> 1) * 8 + q * 2 + (lt & 1);  // global packed tile (r*8+c)
  const int slot = tid & 31;

  float dseg[8];
#pragma unroll
  for (int t = 0; t < 8; ++t) dseg[t] = 1.f - gavg[b * NCn + seg * 8 + t];

  float4* Mf4 = (float4*)Mf;
  // init M = P_{seg-1} quarter (or 0); thread-partitioned -> no barrier needed
  if (seg > 0) {
    UU z; z.u = pbuf4[(size_t)(b * 15 + seg - 1) * 2048 + gtile * 32 + slot];
#pragma unroll
    for (int h2 = 0; h2 < 2; ++h2) {
      float4 mv = {(float)z.h[2 * h2][0], (float)z.h[2 * h2][1],
                   (float)z.h[2 * h2 + 1][0], (float)z.h[2 * h2 + 1][1]};
      Mf4[tid * 2 + h2] = mv;
    }
  } else {
    float4 zz = {0.f, 0.f, 0.f, 0.f};
    Mf4[tid * 2] = zz;
    Mf4[tid * 2 + 1] = zz;
  }

  const uint4* Zseg = wtg4 + (size_t)(b * NCn + seg * 8) * 2048;
  const f16* xhseg = xh + (size_t)(b * NCn + seg * 8) * 8192;

  for (int m = 0; m < 8; ++m) {
    // stage x_c (f16, 2 uint4/thread) and convert M -> f16 (own range)
    {
      const uint4* xs4 = (const uint4*)(xhseg + (size_t)m * 8192);
      int row = tid >> 3, col = (tid & 7) * 16;
      uint4 a = xs4[tid * 2];
      uint4 bq = xs4[tid * 2 + 1];
      *(uint4*)&Xs[row][col] = a;
      *(uint4*)&Xs[row][col + 8] = bq;
    }
#pragma unroll
    for (int h2 = 0; h2 < 2; ++h2) {
      float4 mv = Mf4[tid * 2 + h2];
      f16x4 hh = {(f16)mv.x, (f16)mv.y, (f16)mv.z, (f16)mv.w};
      Mh4[tid * 2 + h2] = hh;
    }
    __syncthreads();  // Xs + Mh visible to all

    // GEMM: out_c tile (mr, q*2+tq) = sum_kk x_c A-frag x M B-frag
    f32x4 acc = {};
#pragma unroll
    for (int kk = 0; kk < 8; ++kk) {
      f16x4 af = *(f16x4*)&Xs[mr * 16 + r16][kk * 16 + g4 * 4];
      f16x4 bf = Mh4[(kk * 2 + tq) * 64 + lane];
      acc = mfma16(af, bf, acc);
    }

    // load Z_c quarter, update M (own range; others still reading Mh4 - fine)
    {
      UU z; z.u = Zseg[(size_t)m * 2048 + gtile * 32 + slot];
      float dd = dseg[m];
#pragma unroll
      for (int h2 = 0; h2 < 2; ++h2) {
        float4 mv = Mf4[tid * 2 + h2];
        mv.x = dd * mv.x + (float)z.h[2 * h2][0];
        mv.y = dd * mv.y + (float)z.h[2 * h2][1];
        mv.z = dd * mv.z + (float)z.h[2 * h2 + 1][0];
        mv.w = dd * mv.w + (float)z.h[2 * h2 + 1][1];
        Mf4[tid * 2 + h2] = mv;
      }
    }

    // store out tile (same validated D-frag scatter as r7)
    {
      const int c = seg * 8 + m;
      float* ob = outp + ((size_t)b * Sn + (size_t)c * 64 + mr * 16 + g4 * 4) * Dn +
                  (q * 2 + tq) * 16 + r16;
#pragma unroll
      for (int j = 0; j < 4; ++j) ob[(size_t)j * Dn] = acc[j];
    }
    __syncthreads();  // all GEMM reads of Xs/Mh4 done before next iter overwrites
  }
}

extern "C" void kernel_launch(void* const* d_in, const int* in_sizes, int n_in,
                              void* d_out, int out_size, void* d_ws, size_t ws_size,
                              hipStream_t stream) {
  const float* x = (const float*)d_in[0];
  const float* Wq = (const float*)d_in[1];
  const float* Wk = (const float*)d_in[2];
  const float* Wv = (const float*)d_in[3];
  const float* gw = (const float*)d_in[4];
  const float* gb = (const float*)d_in[5];
  const float* Wout = (const float*)d_in[6];

  char* ws = (char*)d_ws;
  f16* Amat = (f16*)(ws + 0);                       // 32 KB
  f16* r2 = (f16*)(ws + 32768);                     // 32 KB
  float* gavg = (float*)(ws + 65536);               // 4 KB
  f16* wtg = (f16*)(ws + 69632);                    // 33.5 MB (Z, packed frags)
  f16* pbuf = (f16*)(ws + 33624064);                // 3.93 MB (segment carries)
  f16* xh = (f16*)(ws + 37556224);                  // 16.8 MB (x in f16)

  k_prep<<<dim3(128), dim3(64), 0, stream>>>(Wq, Wk, Wv, Wout, Amat, r2);
  k_phase1<<<dim3(Bn * NCn), dim3(512), 0, stream>>>(x, gw, gb, Amat, r2, (f16x4*)wtg,
                                                     gavg, xh);
  k_scan<<<dim3(256), dim3(256), 0, stream>>>((const uint*)wtg, gavg, (uint*)pbuf);
  k_outseg<<<dim3(512), dim3(512), 0, stream>>>(xh, (const uint4*)wtg, (const uint4*)pbuf,
                                                gavg, (float*)d_out);
}

// Round 10
// 62.556 us; speedup vs baseline: 3.6226x; 1.0379x over previous
//
#include <hip/hip_runtime.h>

#define Bn 8
#define Sn 8192
#define Dn 128
#define NCn 128

typedef _Float16 f16;
typedef f16 f16x2 __attribute__((ext_vector_type(2)));
typedef f16 f16x4 __attribute__((ext_vector_type(4)));
typedef float f32x4 __attribute__((ext_vector_type(4)));

static __device__ __forceinline__ f32x4 mfma16(f16x4 a, f16x4 b, f32x4 c) {
  return __builtin_amdgcn_mfma_f32_16x16x16f16(a, b, c, 0, 0, 0);
}

union UU { uint4 u; f16x2 h[4]; f16x4 q[2]; };

// Validated fragment conventions for mfma_f32_16x16x16f16 (rounds 0,2,3,4,6,7,9):
//   A-frag: lane l, reg j = A_op[l&15][4*(l>>4)+j]
//   B-frag: lane l, reg j = B_op[4*(l>>4)+j][l&15]
//   D-frag: lane l, reg j = D[4*(l>>4)+j][l&15]
//   D-frag of u == A-frag of u^T (in-register); packed D-frag [(r*8+c)*64+lane]
//   == B-frag for row-contraction (validated rounds 3-9).

// ---- precompute: 128 blocks x 1 wave (validated r7-r9) ----
__global__ __launch_bounds__(64) void k_prep(
    const float* __restrict__ Wq, const float* __restrict__ Wk,
    const float* __restrict__ Wv, const float* __restrict__ Wout,
    f16* __restrict__ Amat, f16* __restrict__ r2) {
  const int blk = blockIdx.x;
  const int which = blk >> 6;
  const int t = blk & 63, ti = t >> 3, tj = t & 7;
  const int lane = threadIdx.x & 63, r16 = lane & 15, g4 = lane >> 4;
  f32x4 acc = {};
  if (which == 0) {
#pragma unroll
    for (int kk = 0; kk < 8; ++kk) {
      f16x4 af, bf;
#pragma unroll
      for (int j = 0; j < 4; ++j) {
        af[j] = (f16)Wq[(kk * 16 + g4 * 4 + j) * 128 + ti * 16 + r16];
        bf[j] = (f16)Wk[(kk * 16 + g4 * 4 + j) * 128 + tj * 16 + r16];
      }
      acc = mfma16(af, bf, acc);
    }
  } else {
#pragma unroll
    for (int kk = 0; kk < 8; ++kk) {
      f16x4 af, bf;
      float4 a4 = *(const float4*)(Wout + (ti * 16 + r16) * 128 + kk * 16 + g4 * 4);
      af[0] = (f16)a4.x; af[1] = (f16)a4.y; af[2] = (f16)a4.z; af[3] = (f16)a4.w;
#pragma unroll
      for (int j = 0; j < 4; ++j)
        bf[j] = (f16)Wv[(kk * 16 + g4 * 4 + j) * 128 + tj * 16 + r16];
      acc = mfma16(af, bf, acc);
    }
  }
  f16* dst = which ? r2 : Amat;
#pragma unroll
  for (int j = 0; j < 4; ++j)
    dst[(ti * 16 + g4 * 4 + j) * 128 + tj * 16 + r16] = (f16)acc[j];
}

// ---- fused: gate, u = x Amat^T, v = x r2^T, Z = (g.u)^T v + xh copy (validated r9) ----
__global__ __launch_bounds__(512, 8) void k_phase1(
    const float* __restrict__ x, const float* __restrict__ gw, const float* __restrict__ gb,
    const f16* __restrict__ Amat, const f16* __restrict__ r2,
    f16x4* __restrict__ wtg, float* __restrict__ gavg, f16* __restrict__ xh) {
  __shared__ __align__(16) f16 Xs[64][136];
  __shared__ __align__(16) f16x4 vP[2048];
  __shared__ float gs[64];
  const int h = blockIdx.x;
  const int grp = h & 127, m = h >> 7;
  const int b = grp >> 4, seg = grp & 15;
  const int c = seg * 8 + m;
  const int tid = threadIdx.x;
  {
    int s = tid >> 3, sub = tid & 7;
    const float* xrow = x + ((size_t)b * Sn + (size_t)c * 64 + s) * Dn;
    f16* xhrow = xh + (size_t)(b * NCn + c) * 8192 + s * 128;
    float gpart = 0.f;
#pragma unroll
    for (int i = 0; i < 4; ++i) {
      int col = sub * 4 + i * 32;
      float4 v = *(const float4*)(xrow + col);
      float4 g = *(const float4*)(gw + col);
      gpart += v.x * g.x + v.y * g.y + v.z * g.z + v.w * g.w;
      f16x4 hh = {(f16)v.x, (f16)v.y, (f16)v.z, (f16)v.w};
      *(f16x4*)&Xs[s][col] = hh;
      *(f16x4*)&xhrow[col] = hh;
    }
    gpart += __shfl_xor(gpart, 1);
    gpart += __shfl_xor(gpart, 2);
    gpart += __shfl_xor(gpart, 4);
    if (sub == 0) gs[s] = 1.f / (1.f + __expf(-(gpart + gb[0])));
  }
  __syncthreads();
  if (tid == 0) {
    float sum = 0.f;
#pragma unroll
    for (int i = 0; i < 64; ++i) sum += gs[i];
    gavg[b * NCn + c] = sum * (1.f / 64.f);
  }
  const int w = tid >> 6, lane = tid & 63, r16 = lane & 15, g4 = lane >> 4;
  f32x4 uacc[4] = {}, vacc[4] = {};
#pragma unroll
  for (int kk = 0; kk < 8; ++kk) {
    f16x4 bu = *(const f16x4*)&Amat[(w * 16 + r16) * 128 + kk * 16 + g4 * 4];
    f16x4 bv = *(const f16x4*)&r2[(w * 16 + r16) * 128 + kk * 16 + g4 * 4];
#pragma unroll
    for (int mr = 0; mr < 4; ++mr) {
      f16x4 af = *(f16x4*)&Xs[mr * 16 + r16][kk * 16 + g4 * 4];
      uacc[mr] = mfma16(af, bu, uacc[mr]);
      vacc[mr] = mfma16(af, bv, vacc[mr]);
    }
  }
  f16x4 ua[4];
#pragma unroll
  for (int mr = 0; mr < 4; ++mr) {
    float g0 = gs[mr * 16 + g4 * 4 + 0], g1 = gs[mr * 16 + g4 * 4 + 1];
    float g2 = gs[mr * 16 + g4 * 4 + 2], g3 = gs[mr * 16 + g4 * 4 + 3];
    f16x4 uh = {(f16)(uacc[mr][0] * g0), (f16)(uacc[mr][1] * g1),
                (f16)(uacc[mr][2] * g2), (f16)(uacc[mr][3] * g3)};
    ua[mr] = uh;
    f16x4 vh = {(f16)vacc[mr][0], (f16)vacc[mr][1], (f16)vacc[mr][2], (f16)vacc[mr][3]};
    vP[(mr * 8 + w) * 64 + lane] = vh;
  }
  __syncthreads();
  f32x4 z[8] = {};
#pragma unroll
  for (int ks = 0; ks < 4; ++ks)
#pragma unroll
    for (int ct = 0; ct < 8; ++ct)
      z[ct] = mfma16(ua[ks], vP[(ks * 8 + ct) * 64 + lane], z[ct]);
  f16x4* wdst = wtg + (size_t)(b * NCn + c) * 4096;
#pragma unroll
  for (int ct = 0; ct < 8; ++ct) {
    f16x4 zh = {(f16)z[ct][0], (f16)z[ct][1], (f16)z[ct][2], (f16)z[ct][3]};
    wdst[(w * 8 + ct) * 64 + lane] = zh;
  }
}

// ---- out + integrated carry fold. Block (b,seg,q) computes P_{seg-1} by
// folding Z[0..8*seg) quarters in f32 regs (r7 recurrence, validated), then
// runs the r9 m-loop with T14 reg-prefetch of next x chunk + early Z issue.
// Blocks launched seg-DESCENDING so heavy folds start first. ----
__global__ __launch_bounds__(512, 4) void k_outfold(
    const f16* __restrict__ xh, const uint4* __restrict__ wtg4,
    const float* __restrict__ gavg, float* __restrict__ outp) {
  __shared__ __align__(16) f16 Xs[64][136];   // 17408 B
  __shared__ __align__(16) float Mf[4096];    // 16384 B (f32 accumulator, packed)
  __shared__ __align__(16) f16x4 Mh4[1024];   // 8192 B  (f16 copy for GEMM)
  const int blk = blockIdx.x;
  const int seg = 15 - (blk >> 5);            // seg-descending schedule
  const int sub5 = blk & 31;
  const int b = sub5 >> 2, q = sub5 & 3;
  const int tid = threadIdx.x;
  const int w = tid >> 6, lane = tid & 63, r16 = lane & 15, g4 = lane >> 4;
  const int mr = w & 3, tq = w >> 2;          // wave tile: rows mr*16.., col q*2+tq

  const int lt = tid >> 5;                    // local tile 0..15
  const int gtile = (lt >> 1) * 8 + q * 2 + (lt & 1);
  const int slot = tid & 31;

  // ---- carry fold: P = sum over t<8*seg of decayed Z_t (own quarter slots) ----
  float4 P0 = {0.f, 0.f, 0.f, 0.f}, P1 = {0.f, 0.f, 0.f, 0.f};
  {
    const uint4* Zb = wtg4 + (size_t)(b * NCn) * 2048 + gtile * 32 + slot;
    const float* ga = gavg + b * NCn;
    const int nt = seg * 8;
#pragma unroll 4
    for (int t = 0; t < nt; ++t) {
      UU z; z.u = Zb[(size_t)t * 2048];
      float dd = 1.f - ga[t];
      P0.x = dd * P0.x + (float)z.h[0][0];
      P0.y = dd * P0.y + (float)z.h[0][1];
      P0.z = dd * P0.z + (float)z.h[1][0];
      P0.w = dd * P0.w + (float)z.h[1][1];
      P1.x = dd * P1.x + (float)z.h[2][0];
      P1.y = dd * P1.y + (float)z.h[2][1];
      P1.z = dd * P1.z + (float)z.h[3][0];
      P1.w = dd * P1.w + (float)z.h[3][1];
    }
  }
  float4* Mf4 = (float4*)Mf;
  Mf4[tid * 2] = P0;          // thread-owned slots: no barrier needed (r9 pattern)
  Mf4[tid * 2 + 1] = P1;

  float dseg[8];
#pragma unroll
  for (int t = 0; t < 8; ++t) dseg[t] = 1.f - gavg[b * NCn + seg * 8 + t];

  const uint4* Zseg = wtg4 + (size_t)(b * NCn + seg * 8) * 2048;
  const f16* xhseg = xh + (size_t)(b * NCn + seg * 8) * 8192;
  const int xrow = tid >> 3, xcol = (tid & 7) * 16;

  // T14: preload chunk 0's x into regs
  uint4 xa = ((const uint4*)xhseg)[tid * 2];
  uint4 xb2 = ((const uint4*)xhseg)[tid * 2 + 1];

  for (int m = 0; m < 8; ++m) {
    // write staged x (regs -> LDS) and convert M -> f16 (own range)
    *(uint4*)&Xs[xrow][xcol] = xa;
    *(uint4*)&Xs[xrow][xcol + 8] = xb2;
#pragma unroll
    for (int h2 = 0; h2 < 2; ++h2) {
      float4 mv = Mf4[tid * 2 + h2];
      f16x4 hh = {(f16)mv.x, (f16)mv.y, (f16)mv.z, (f16)mv.w};
      Mh4[tid * 2 + h2] = hh;
    }
    __syncthreads();  // Xs + Mh visible to all

    // early-issue: this chunk's Z + next chunk's x (overlap with MFMAs below)
    UU z;
    z.u = Zseg[(size_t)m * 2048 + gtile * 32 + slot];
    if (m < 7) {
      const uint4* xn = (const uint4*)(xhseg + (size_t)(m + 1) * 8192);
      xa = xn[tid * 2];
      xb2 = xn[tid * 2 + 1];
    }

    // GEMM: out_c tile (mr, q*2+tq)
    f32x4 acc = {};
#pragma unroll
    for (int kk = 0; kk < 8; ++kk) {
      f16x4 af = *(f16x4*)&Xs[mr * 16 + r16][kk * 16 + g4 * 4];
      f16x4 bf = Mh4[(kk * 2 + tq) * 64 + lane];
      acc = mfma16(af, bf, acc);
    }

    // M update (own slots; others only read Mh4 - safe)
    {
      float dd = dseg[m];
#pragma unroll
      for (int h2 = 0; h2 < 2; ++h2) {
        float4 mv = Mf4[tid * 2 + h2];
        mv.x = dd * mv.x + (float)z.h[2 * h2][0];
        mv.y = dd * mv.y + (float)z.h[2 * h2][1];
        mv.z = dd * mv.z + (float)z.h[2 * h2 + 1][0];
        mv.w = dd * mv.w + (float)z.h[2 * h2 + 1][1];
        Mf4[tid * 2 + h2] = mv;
      }
    }

    // store out tile (validated D-frag scatter)
    {
      const int c = seg * 8 + m;
      float* ob = outp + ((size_t)b * Sn + (size_t)c * 64 + mr * 16 + g4 * 4) * Dn +
                  (q * 2 + tq) * 16 + r16;
#pragma unroll
      for (int j = 0; j < 4; ++j) ob[(size_t)j * Dn] = acc[j];
    }
    __syncthreads();  // all GEMM reads of Xs/Mh4 done before next overwrite
  }
}

extern "C" void kernel_launch(void* const* d_in, const int* in_sizes, int n_in,
                              void* d_out, int out_size, void* d_ws, size_t ws_size,
                              hipStream_t stream) {
  const float* x = (const float*)d_in[0];
  const float* Wq = (const float*)d_in[1];
  const float* Wk = (const float*)d_in[2];
  const float* Wv = (const float*)d_in[3];
  const float* gw = (const float*)d_in[4];
  const float* gb = (const float*)d_in[5];
  const float* Wout = (const float*)d_in[6];

  char* ws = (char*)d_ws;
  f16* Amat = (f16*)(ws + 0);                       // 32 KB
  f16* r2 = (f16*)(ws + 32768);                     // 32 KB
  float* gavg = (float*)(ws + 65536);               // 4 KB
  f16* wtg = (f16*)(ws + 69632);                    // 33.5 MB (Z, packed frags)
  f16* xh = (f16*)(ws + 37556224);                  // 16.8 MB (x in f16)

  k_prep<<<dim3(128), dim3(64), 0, stream>>>(Wq, Wk, Wv, Wout, Amat, r2);
  k_phase1<<<dim3(Bn * NCn), dim3(512), 0, stream>>>(x, gw, gb, Amat, r2, (f16x4*)wtg,
                                                     gavg, xh);
  k_outfold<<<dim3(512), dim3(512), 0, stream>>>(xh, (const uint4*)wtg, gavg,
                                                 (float*)d_out);
}